// Round 3
// baseline (135.844 us; speedup 1.0000x reference)
//
#include <hip/hip_runtime.h>

#define NROWS 16384
#define MREF 4096
#define NLAYER 8
#define BLOCK 256

#define RPT 4                       // rows per thread in main kernel
#define MCHUNK 128                  // m elements per block
#define MCHUNKS (MREF / MCHUNK)     // 32
#define NSEG (NROWS / RPT)          // 4096: row stride between a thread's rows
#define SEGS (NSEG / BLOCK)         // 16 row-segments

// ws layout (float offsets), no zero-init needed except tiny counters:
//   rowc  float4[NROWS]           @ 0          (256 KB)
//   refc  float4[MREF]            @ 65536      (64 KB)
//   part  float4[MCHUNKS*NSEG]    @ 81920      (2 MB)  -- unique-slot partials
//   cnt   int[SEGS]               @ 606208     (zeroed by prep)
#define WS_ROWC 0
#define WS_REFC (NROWS * 4)
#define WS_PART (NROWS * 4 + MREF * 4)
#define WS_CNT  (WS_PART + MCHUNKS * NSEG * 4)

// k(n,m) = exp(2*(a.b) - 4) since ||a||^2 = ||b||^2 = 2 exactly (a=[sin,cos]).
// a-side coeffs pre-scaled by 2*log2(e); accumulate exp2(dot); fold exp(-4)/M
// into the fused epilogue.

__global__ __launch_bounds__(BLOCK) void prep(
    const float* __restrict__ x,
    const float* __restrict__ layer_W,
    const float* __restrict__ layer_b,
    const float* __restrict__ layer_scale,
    const float* __restrict__ layer_shift,
    const float* __restrict__ refset,
    float* __restrict__ ws)
{
    const int n = blockIdx.x * BLOCK + threadIdx.x;

    // zero the per-segment arrival counters (ws is poisoned 0xAA each launch)
    if (n < SEGS) ((int*)&ws[WS_CNT])[n] = 0;

    // 8-layer chain (params wave-uniform -> scalar loads)
    float h0 = x[n * 2 + 0];
    float h1 = x[n * 2 + 1];
#pragma unroll
    for (int l = 0; l < NLAYER; ++l) {
        const float w00 = layer_W[l * 4 + 0];
        const float w01 = layer_W[l * 4 + 1];
        const float w10 = layer_W[l * 4 + 2];
        const float w11 = layer_W[l * 4 + 3];
        const float b0 = layer_b[l * 2 + 0];
        const float b1 = layer_b[l * 2 + 1];
        const float s0 = layer_scale[l * 2 + 0];
        const float s1 = layer_scale[l * 2 + 1];
        const float t0 = layer_shift[l * 2 + 0];
        const float t1 = layer_shift[l * 2 + 1];
        const float n0 = fmaf(tanhf(fmaf(h1, w01, fmaf(h0, w00, b0))), s0, t0);
        const float n1 = fmaf(tanhf(fmaf(h1, w11, fmaf(h0, w10, b1))), s1, t1);
        h0 = n0; h1 = n1;
    }

    float sf0, cf0, sf1, cf1;
    sincosf(h0, &sf0, &cf0);
    sincosf(h1, &sf1, &cf1);

    const float L2E2 = 2.0f * 1.4426950408889634f;  // 2*log2(e)
    float4* rowc = (float4*)&ws[WS_ROWC];
    float4 rc; rc.x = sf0 * L2E2; rc.y = sf1 * L2E2; rc.z = cf0 * L2E2; rc.w = cf1 * L2E2;
    rowc[n] = rc;

    if (n < MREF) {
        const float r0 = refset[n * 2 + 0];
        const float r1 = refset[n * 2 + 1];
        float s0, c0, s1, c1;
        sincosf(r0, &s0, &c0);
        sincosf(r1, &s1, &c1);
        float4* refc = (float4*)&ws[WS_REFC];
        float4 v; v.x = s0; v.y = s1; v.z = c0; v.w = c1;
        refc[n] = v;
    }
}

__global__ __launch_bounds__(BLOCK) void pair_sum(
    float* __restrict__ ws,
    const float* __restrict__ W1,
    const float* __restrict__ b1,
    const float* __restrict__ W2,
    const float* __restrict__ b2,
    float* __restrict__ out)
{
    __shared__ float4 sref[MCHUNK];
    __shared__ bool amLast;

    const int tid = threadIdx.x;
    const int seg = blockIdx.x;          // [0, SEGS)
    const int y = blockIdx.y;            // [0, MCHUNKS)
    const int mbase = y * MCHUNK;

    const float4* __restrict__ refc = (const float4*)&ws[WS_REFC];
    const float4* __restrict__ rowc = (const float4*)&ws[WS_ROWC];
    float4* __restrict__ part = (float4*)&ws[WS_PART];
    int* __restrict__ cnt = (int*)&ws[WS_CNT];

    if (tid < MCHUNK) sref[tid] = refc[mbase + tid];

    const int base = seg * BLOCK + tid;  // [0, NSEG)

    float4 c0 = rowc[base + 0 * NSEG];
    float4 c1 = rowc[base + 1 * NSEG];
    float4 c2 = rowc[base + 2 * NSEG];
    float4 c3 = rowc[base + 3 * NSEG];

    __syncthreads();

    float a0 = 0.0f, a1 = 0.0f, a2 = 0.0f, a3 = 0.0f;
#pragma unroll 4
    for (int i = 0; i < MCHUNK; ++i) {
        const float4 v = sref[i];  // wave-uniform -> LDS broadcast
        float d0 = c0.x * v.x; d0 = fmaf(c0.y, v.y, d0); d0 = fmaf(c0.z, v.z, d0); d0 = fmaf(c0.w, v.w, d0);
        float d1 = c1.x * v.x; d1 = fmaf(c1.y, v.y, d1); d1 = fmaf(c1.z, v.z, d1); d1 = fmaf(c1.w, v.w, d1);
        float d2 = c2.x * v.x; d2 = fmaf(c2.y, v.y, d2); d2 = fmaf(c2.z, v.z, d2); d2 = fmaf(c2.w, v.w, d2);
        float d3 = c3.x * v.x; d3 = fmaf(c3.y, v.y, d3); d3 = fmaf(c3.z, v.z, d3); d3 = fmaf(c3.w, v.w, d3);
        a0 += exp2f(d0);
        a1 += exp2f(d1);
        a2 += exp2f(d2);
        a3 += exp2f(d3);
    }

    // unique-slot partial: no init, no atomic contention
    float4 mine; mine.x = a0; mine.y = a1; mine.z = a2; mine.w = a3;
    part[y * NSEG + base] = mine;

    // last-block-done: the 32nd block for this segment runs the epilogue
    __threadfence();
    __syncthreads();
    if (tid == 0) {
        const int old = atomicAdd(&cnt[seg], 1);
        amLast = (old == MCHUNKS - 1);
    }
    __syncthreads();

    if (amLast) {
        __threadfence();  // acquire: see all other blocks' partials
        float4 s; s.x = 0.0f; s.y = 0.0f; s.z = 0.0f; s.w = 0.0f;
#pragma unroll
        for (int y2 = 0; y2 < MCHUNKS; ++y2) {
            const float4 p = part[y2 * NSEG + base];  // coalesced across tid
            s.x += p.x; s.y += p.y; s.z += p.z; s.w += p.w;
        }

        // epilogue: mean = s * exp(-4)/M; tanh MLP; softmax
        const float C = 1.8315638888734179e-2f / (float)MREF;  // exp(-4)/M
        const float w1_0 = W1[0], w1_1 = W1[1], w1_2 = W1[2], w1_3 = W1[3];
        const float b1_0 = b1[0], b1_1 = b1[1], b1_2 = b1[2], b1_3 = b1[3];
        const float agg[RPT] = { s.x * C, s.y * C, s.z * C, s.w * C };
#pragma unroll
        for (int j = 0; j < RPT; ++j) {
            const float h0 = tanhf(fmaf(agg[j], w1_0, b1_0));
            const float h1 = tanhf(fmaf(agg[j], w1_1, b1_1));
            const float h2 = tanhf(fmaf(agg[j], w1_2, b1_2));
            const float h3 = tanhf(fmaf(agg[j], w1_3, b1_3));
            float l0 = b2[0], l1 = b2[1];
            l0 = fmaf(W2[0], h0, l0); l0 = fmaf(W2[1], h1, l0);
            l0 = fmaf(W2[2], h2, l0); l0 = fmaf(W2[3], h3, l0);
            l1 = fmaf(W2[4], h0, l1); l1 = fmaf(W2[5], h1, l1);
            l1 = fmaf(W2[6], h2, l1); l1 = fmaf(W2[7], h3, l1);
            const float mx = fmaxf(l0, l1);
            const float e0 = __expf(l0 - mx);
            const float e1 = __expf(l1 - mx);
            const float inv = 1.0f / (e0 + e1);
            const int row = base + j * NSEG;
            out[2 * row + 0] = e0 * inv;
            out[2 * row + 1] = e1 * inv;
        }
    }
}

extern "C" void kernel_launch(void* const* d_in, const int* in_sizes, int n_in,
                              void* d_out, int out_size, void* d_ws, size_t ws_size,
                              hipStream_t stream) {
    const float* x           = (const float*)d_in[0];
    const float* layer_W     = (const float*)d_in[1];
    const float* layer_b     = (const float*)d_in[2];
    const float* layer_scale = (const float*)d_in[3];
    const float* layer_shift = (const float*)d_in[4];
    const float* refset      = (const float*)d_in[5];
    const float* W1          = (const float*)d_in[6];
    const float* b1          = (const float*)d_in[7];
    const float* W2          = (const float*)d_in[8];
    const float* b2          = (const float*)d_in[9];
    float* out = (float*)d_out;
    float* ws  = (float*)d_ws;

    prep<<<NROWS / BLOCK, BLOCK, 0, stream>>>(x, layer_W, layer_b, layer_scale,
                                              layer_shift, refset, ws);

    dim3 grid(SEGS, MCHUNKS);  // 16 x 32 = 512 blocks
    pair_sum<<<grid, BLOCK, 0, stream>>>(ws, W1, b1, W2, b2, out);
}

// Round 4
// 80.268 us; speedup vs baseline: 1.6924x; 1.6924x over previous
//
#include <hip/hip_runtime.h>

#define NROWS 16384
#define MREF 4096
#define NLAYER 8
#define BLOCK 256

#define KSER 8              // Fourier terms k = 0..7 (tail 2*I8(2) ~ 5.5e-5)
#define DIM 16              // 8 cos + 8 sin features per angle
#define MB 64               // blocks in moments kernel
#define MPB (MREF / MB)     // 64 ref points per block

// ws layout: part[MB*256] floats (unique-slot M partials; no init needed)

// Jacobi-Anger: exp(2*cos(t)) = c0 + sum_k ck*cos(k t), ck = 2*Ik(2).
// k(n,m) = exp(-||a-b||^2) = e^-4 * exp(2cos(f0-r0)) * exp(2cos(f1-r1))
// sum_m factorizes: S(n) = p(f0)^T M p(f1),  M = sum_m q(r0m) q(r1m)^T (16x16).

__device__ __forceinline__ void fill_q(float ang, float* qrow) {
    float s, c;
    sincosf(ang, &s, &c);
    qrow[0] = 1.0f; qrow[8] = 0.0f;
    qrow[1] = c;    qrow[9] = s;
    float ckm1 = 1.0f, skm1 = 0.0f, ck = c, sk = s;
#pragma unroll
    for (int k = 2; k < KSER; ++k) {
        const float cn = fmaf(2.0f * c, ck, -ckm1);
        const float sn = fmaf(2.0f * c, sk, -skm1);
        ckm1 = ck; skm1 = sk; ck = cn; sk = sn;
        qrow[k] = ck; qrow[8 + k] = sk;
    }
}

__device__ __forceinline__ void fill_p(float ang, float* p) {
    // ck = 2*Ik(2) for k>=1, c0 = I0(2)
    const float C0 = 2.2795853023360673f;
    const float CK[8] = {0.0f, 3.1812737092746582f, 1.3778968953974764f,
                         0.42547991847970535f, 0.10145713995836048f,
                         0.019651358646263404f, 0.0032003467270434532f,
                         0.00044977322954295146f};
    float s, c;
    sincosf(ang, &s, &c);
    p[0] = C0;        p[8] = 0.0f;
    p[1] = CK[1] * c; p[9] = CK[1] * s;
    float ckm1 = 1.0f, skm1 = 0.0f, ck = c, sk = s;
#pragma unroll
    for (int k = 2; k < KSER; ++k) {
        const float cn = fmaf(2.0f * c, ck, -ckm1);
        const float sn = fmaf(2.0f * c, sk, -skm1);
        ckm1 = ck; skm1 = sk; ck = cn; sk = sn;
        p[k] = CK[k] * ck; p[8 + k] = CK[k] * sk;
    }
}

__global__ __launch_bounds__(BLOCK) void moments(
    const float* __restrict__ refset,
    float* __restrict__ part)
{
    __shared__ float q0[MPB][DIM + 1];
    __shared__ float q1[MPB][DIM + 1];

    const int tid = threadIdx.x;
    const int mbase = blockIdx.x * MPB;

    if (tid < MPB) {
        const float2 r = ((const float2*)refset)[mbase + tid];
        fill_q(r.x, &q0[tid][0]);
        fill_q(r.y, &q1[tid][0]);
    }
    __syncthreads();

    // thread (i,j) accumulates M_ij partial over this block's MPB refs.
    // q0 read: 4 distinct i per wave (16-lane broadcast groups); q1 read:
    // 16 distinct j -> 16 consecutive banks. No conflicts.
    const int i = tid >> 4;
    const int j = tid & 15;
    float acc = 0.0f;
#pragma unroll 8
    for (int m = 0; m < MPB; ++m)
        acc = fmaf(q0[m][i], q1[m][j], acc);

    part[blockIdx.x * 256 + tid] = acc;  // unique slot: no init, no atomics
}

__global__ __launch_bounds__(BLOCK) void rows(
    const float* __restrict__ x,
    const float* __restrict__ layer_W,
    const float* __restrict__ layer_b,
    const float* __restrict__ layer_scale,
    const float* __restrict__ layer_shift,
    const float* __restrict__ part,
    const float* __restrict__ W1,
    const float* __restrict__ b1,
    const float* __restrict__ W2,
    const float* __restrict__ b2,
    float2* __restrict__ out)
{
    __shared__ float Msh[DIM * DIM];

    const int tid = threadIdx.x;
    const int n = blockIdx.x * BLOCK + tid;

    // per-block reduction of the 64 unique-slot partials (coalesced, L2-hot)
    float msum = 0.0f;
#pragma unroll 8
    for (int b = 0; b < MB; ++b)
        msum += part[b * 256 + tid];
    Msh[tid] = msum;

    // 8-layer chain (params wave-uniform -> scalar loads)
    const float2 xin = ((const float2*)x)[n];
    float h0 = xin.x, h1 = xin.y;
#pragma unroll
    for (int l = 0; l < NLAYER; ++l) {
        const float w00 = layer_W[l * 4 + 0];
        const float w01 = layer_W[l * 4 + 1];
        const float w10 = layer_W[l * 4 + 2];
        const float w11 = layer_W[l * 4 + 3];
        const float bb0 = layer_b[l * 2 + 0];
        const float bb1 = layer_b[l * 2 + 1];
        const float s0 = layer_scale[l * 2 + 0];
        const float s1 = layer_scale[l * 2 + 1];
        const float t0 = layer_shift[l * 2 + 0];
        const float t1 = layer_shift[l * 2 + 1];
        const float n0 = fmaf(tanhf(fmaf(h1, w01, fmaf(h0, w00, bb0))), s0, t0);
        const float n1 = fmaf(tanhf(fmaf(h1, w11, fmaf(h0, w10, bb1))), s1, t1);
        h0 = n0; h1 = n1;
    }

    float p0[DIM], p1[DIM];
    fill_p(h0, p0);
    fill_p(h1, p1);

    __syncthreads();

    // S = p0^T M p1 (M reads are wave-uniform -> LDS broadcast)
    float S = 0.0f;
#pragma unroll
    for (int i = 0; i < DIM; ++i) {
        float t = 0.0f;
#pragma unroll
        for (int j = 0; j < DIM; ++j)
            t = fmaf(Msh[i * DIM + j], p1[j], t);
        S = fmaf(p0[i], t, S);
    }

    // mean k = S * exp(-4) / M
    const float agg = S * (1.8315638888734179e-2f / (float)MREF);

    const float g0 = tanhf(fmaf(agg, W1[0], b1[0]));
    const float g1 = tanhf(fmaf(agg, W1[1], b1[1]));
    const float g2 = tanhf(fmaf(agg, W1[2], b1[2]));
    const float g3 = tanhf(fmaf(agg, W1[3], b1[3]));
    float l0 = b2[0], l1 = b2[1];
    l0 = fmaf(W2[0], g0, l0); l0 = fmaf(W2[1], g1, l0);
    l0 = fmaf(W2[2], g2, l0); l0 = fmaf(W2[3], g3, l0);
    l1 = fmaf(W2[4], g0, l1); l1 = fmaf(W2[5], g1, l1);
    l1 = fmaf(W2[6], g2, l1); l1 = fmaf(W2[7], g3, l1);
    const float mx = fmaxf(l0, l1);
    const float e0 = __expf(l0 - mx);
    const float e1 = __expf(l1 - mx);
    const float inv = 1.0f / (e0 + e1);
    float2 o; o.x = e0 * inv; o.y = e1 * inv;
    out[n] = o;
}

extern "C" void kernel_launch(void* const* d_in, const int* in_sizes, int n_in,
                              void* d_out, int out_size, void* d_ws, size_t ws_size,
                              hipStream_t stream) {
    const float* x           = (const float*)d_in[0];
    const float* layer_W     = (const float*)d_in[1];
    const float* layer_b     = (const float*)d_in[2];
    const float* layer_scale = (const float*)d_in[3];
    const float* layer_shift = (const float*)d_in[4];
    const float* refset      = (const float*)d_in[5];
    const float* W1          = (const float*)d_in[6];
    const float* b1          = (const float*)d_in[7];
    const float* W2          = (const float*)d_in[8];
    const float* b2          = (const float*)d_in[9];
    float2* out = (float2*)d_out;
    float* part = (float*)d_ws;

    moments<<<MB, BLOCK, 0, stream>>>(refset, part);

    rows<<<NROWS / BLOCK, BLOCK, 0, stream>>>(x, layer_W, layer_b, layer_scale,
                                              layer_shift, part, W1, b1, W2, b2, out);
}